// Round 2
// baseline (559.224 us; speedup 1.0000x reference)
//
#include <hip/hip_runtime.h>
#include <hip/hip_bf16.h>

typedef unsigned short u16;
typedef __attribute__((ext_vector_type(8))) short short8;
typedef __attribute__((ext_vector_type(4))) float f32x4;

#define N_INST 2000
#define H_DIM 256
#define D_DIM 64
#define R_DIM 49
#define LN_EPS 1e-5f

__device__ __forceinline__ u16 f2bf(float f) {
  union { float f; unsigned int i; } x; x.f = f;
  unsigned int r = x.i + 0x7fffu + ((x.i >> 16) & 1u);  // RNE
  return (u16)(r >> 16);
}
__device__ __forceinline__ short8 ld8(const u16* p) {
  return *reinterpret_cast<const short8*>(p);
}
// 8 fp32 -> bf16x8 fragment (two float4 loads)
__device__ __forceinline__ short8 ld8f(const float* p) {
  const float4* q = (const float4*)p;
  float4 a = q[0], b = q[1];
  short8 r;
  r[0] = (short)f2bf(a.x); r[1] = (short)f2bf(a.y);
  r[2] = (short)f2bf(a.z); r[3] = (short)f2bf(a.w);
  r[4] = (short)f2bf(b.x); r[5] = (short)f2bf(b.y);
  r[6] = (short)f2bf(b.z); r[7] = (short)f2bf(b.w);
  return r;
}
__device__ __forceinline__ f32x4 mfma16(short8 a, short8 b, f32x4 c) {
  return __builtin_amdgcn_mfma_f32_16x16x32_bf16(a, b, c, 0, 0, 0);
}
__device__ __forceinline__ void wave_reduce2(float& s, float& s2) {
#pragma unroll
  for (int off = 32; off > 0; off >>= 1) {
    s  += __shfl_down(s, off);
    s2 += __shfl_down(s2, off);
  }
  s = __shfl(s, 0); s2 = __shfl(s2, 0);
}

// fp32 -> bf16 cast, float4 grid-stride (n % 4 == 0)
__global__ __launch_bounds__(256) void castk(const float* __restrict__ in,
                                             u16* __restrict__ out, int n4) {
  for (int i = blockIdx.x * 256 + threadIdx.x; i < n4; i += gridDim.x * 256) {
    float4 v = ((const float4*)in)[i];
    union { u16 h[4]; short8 dummy; } o;
    u16* op = out + i * 4;
    op[0] = f2bf(v.x); op[1] = f2bf(v.y); op[2] = f2bf(v.z); op[3] = f2bf(v.w);
    (void)o;
  }
}

// Generic C = A @ B (+bias) GEMM, bf16 in, 64x64 block tile, 4 waves.
// A row-major (lda), frags loaded direct from global (rows clamped to M-1).
// B row-major (ldb), staged transposed into LDS per 32-k-step.
// out_f32=0: bf16 C with fp32 bias; out_f32=1: fp32 partial at Cout + s*c_stride_s.
__global__ __launch_bounds__(256) void gemm_bt(
    const u16* __restrict__ A, int lda, int M,
    const u16* __restrict__ B, int ldb,
    const float* __restrict__ bias,
    void* __restrict__ Cout, int ldc, long c_stride_s,
    int ksteps, int n_blocks, int out_f32)
{
  const int tid  = threadIdx.x;
  const int wave = tid >> 6, lane = tid & 63;
  const int quad = lane >> 4, l16 = lane & 15;
  const int bid  = blockIdx.x;
  const int mblk = bid / n_blocks, nblk = bid - mblk * n_blocks;
  const int m0 = mblk * 64, n0 = nblk * 64;
  const int s  = blockIdx.y;
  const int kb = s * ksteps * 32;

  __shared__ u16 BT[64][40];  // [n][k], row stride 80B (16B-aligned)

  int arow = m0 + wave * 16 + l16;
  if (arow >= M) arow = M - 1;  // clamp: read valid mem, discard at store
  const u16* Arow = A + (long)arow * lda + kb + quad * 8;

  const int bkrow = tid >> 3;
  const int bng   = (tid & 7) * 8;
  const u16* Bp = B + (long)(kb + bkrow) * ldb + n0 + bng;

  f32x4 acc[4];
#pragma unroll
  for (int i = 0; i < 4; ++i) acc[i] = f32x4{0.f, 0.f, 0.f, 0.f};

  for (int ks = 0; ks < ksteps; ++ks) {
    short8 bv = ld8(Bp + (long)ks * 32 * ldb);   // coalesced 16B
#pragma unroll
    for (int j = 0; j < 8; ++j) BT[bng + j][bkrow] = (u16)bv[j];  // transpose
    __syncthreads();
    short8 af = ld8(Arow + ks * 32);
#pragma unroll
    for (int sub = 0; sub < 4; ++sub) {
      short8 bf = ld8(&BT[sub * 16 + l16][quad * 8]);
      acc[sub] = mfma16(af, bf, acc[sub]);
    }
    __syncthreads();
  }

  if (out_f32) {
    float* Cp = (float*)Cout + (long)s * c_stride_s;
#pragma unroll
    for (int sub = 0; sub < 4; ++sub) {
      int col = n0 + sub * 16 + l16;
#pragma unroll
      for (int i = 0; i < 4; ++i) {
        int row = m0 + wave * 16 + quad * 4 + i;
        if (row < M) Cp[(long)row * ldc + col] = acc[sub][i];
      }
    }
  } else {
    u16* Cp = (u16*)Cout;
#pragma unroll
    for (int sub = 0; sub < 4; ++sub) {
      int col = n0 + sub * 16 + l16;
      float bv = bias ? bias[col] : 0.f;
#pragma unroll
      for (int i = 0; i < 4; ++i) {
        int row = m0 + wave * 16 + quad * 4 + i;
        if (row < M) Cp[(long)row * ldc + col] = f2bf(acc[sub][i] + bv);
      }
    }
  }
}

// f1 = feats[n] @ p1[n]; LN over D; ReLU. One block per instance.
// roi is fp32, converted to bf16 at fragment load.
__global__ __launch_bounds__(256) void bmm1_ln(
    const float* __restrict__ roi,  // (R, N, H) fp32
    const u16* __restrict__ P1,     // (N, H, D) bf16
    const float* __restrict__ g1, const float* __restrict__ b1,
    u16* __restrict__ f1n)          // (N, R, D) bf16
{
  const int n = blockIdx.x;
  const int tid = threadIdx.x;
  const int wave = tid >> 6, lane = tid & 63;
  const int quad = lane >> 4, l16 = lane & 15;

  __shared__ u16 BT[D_DIM][H_DIM + 8];   // p1^T: [d][h], 33.8 KB
  __shared__ float Cb[64][D_DIM];        // 16 KB

  const u16* P1n = P1 + (long)n * (H_DIM * D_DIM);
#pragma unroll
  for (int i = 0; i < 8; ++i) {
    int vec = tid + 256 * i;
    int h = vec >> 3;
    int dg = (vec & 7) * 8;
    short8 v = ld8(P1n + h * D_DIM + dg);
#pragma unroll
    for (int j = 0; j < 8; ++j) BT[dg + j][h] = (u16)v[j];
  }
  __syncthreads();

  int r = wave * 16 + l16;
  int rr = (r < R_DIM) ? r : 0;
  const float* Arow = roi + ((long)rr * N_INST + n) * H_DIM + quad * 8;

  f32x4 acc[4];
#pragma unroll
  for (int i = 0; i < 4; ++i) acc[i] = f32x4{0.f, 0.f, 0.f, 0.f};

#pragma unroll
  for (int ks = 0; ks < 8; ++ks) {
    short8 af = ld8f(Arow + ks * 32);
#pragma unroll
    for (int sub = 0; sub < 4; ++sub) {
      short8 bf = ld8(&BT[sub * 16 + l16][ks * 32 + quad * 8]);
      acc[sub] = mfma16(af, bf, acc[sub]);
    }
  }
#pragma unroll
  for (int sub = 0; sub < 4; ++sub)
#pragma unroll
    for (int i = 0; i < 4; ++i)
      Cb[wave * 16 + quad * 4 + i][sub * 16 + l16] = acc[sub][i];
  __syncthreads();

  float gv = g1[lane], bv = b1[lane];
  for (int i = 0; i < 13; ++i) {
    int r2 = wave + 4 * i;             // wave-uniform -> no divergence
    if (r2 < R_DIM) {
      float x = Cb[r2][lane];          // lane = d, exactly 64 values
      float sv = x, s2 = x * x;
      wave_reduce2(sv, s2);
      float mean = sv * (1.f / 64.f);
      float var = s2 * (1.f / 64.f) - mean * mean;
      float rs = rsqrtf(var + LN_EPS);
      float y = fmaxf((x - mean) * rs * gv + bv, 0.f);
      f1n[((long)n * R_DIM + r2) * D_DIM + lane] = f2bf(y);
    }
  }
}

// f2 = f1n[n] @ p2[n]; LN over H; ReLU. One block per instance.
__global__ __launch_bounds__(256) void bmm2_ln(
    const u16* __restrict__ f1n,    // (N, R, D) bf16
    const u16* __restrict__ P2,     // (N, D, H) bf16
    const float* __restrict__ g2, const float* __restrict__ b2,
    u16* __restrict__ f2n)          // (N, R, H) bf16
{
  const int n = blockIdx.x;
  const int tid = threadIdx.x;
  const int wave = tid >> 6, lane = tid & 63;
  const int quad = lane >> 4, l16 = lane & 15;

  // BT (36.9 KB) and Cb (50.2 KB) don't overlap in time -> union, <=64KB static
  union SmemU {
    u16 bt[H_DIM][D_DIM + 8];   // p2^T: [h][d]
    float cb[R_DIM][H_DIM];
  };
  __shared__ SmemU sm;

  const u16* P2n = P2 + (long)n * (D_DIM * H_DIM);
#pragma unroll
  for (int i = 0; i < 8; ++i) {
    int vec = tid + 256 * i;
    int d = vec >> 5;
    int hg = (vec & 31) * 8;
    short8 v = ld8(P2n + d * H_DIM + hg);
#pragma unroll
    for (int j = 0; j < 8; ++j) sm.bt[hg + j][d] = (u16)v[j];
  }
  __syncthreads();

  int r = wave * 16 + l16;
  int rr = (r < R_DIM) ? r : 0;
  const u16* Arow = f1n + ((long)n * R_DIM + rr) * D_DIM + quad * 8;

  f32x4 acc[16];
#pragma unroll
  for (int i = 0; i < 16; ++i) acc[i] = f32x4{0.f, 0.f, 0.f, 0.f};

#pragma unroll
  for (int ks = 0; ks < 2; ++ks) {
    short8 af = ld8(Arow + ks * 32);
#pragma unroll
    for (int sub = 0; sub < 16; ++sub) {
      short8 bf = ld8(&sm.bt[sub * 16 + l16][ks * 32 + quad * 8]);
      acc[sub] = mfma16(af, bf, acc[sub]);
    }
  }
  __syncthreads();   // all BT reads done before cb overwrites it
#pragma unroll
  for (int sub = 0; sub < 16; ++sub)
#pragma unroll
    for (int i = 0; i < 4; ++i) {
      int row = wave * 16 + quad * 4 + i;
      if (row < R_DIM) sm.cb[row][sub * 16 + l16] = acc[sub][i];
    }
  __syncthreads();

  for (int i = 0; i < 13; ++i) {
    int r2 = wave + 4 * i;
    if (r2 < R_DIM) {
      float x[4], sv = 0.f, s2 = 0.f;
#pragma unroll
      for (int j = 0; j < 4; ++j) {
        x[j] = sm.cb[r2][lane + 64 * j];
        sv += x[j]; s2 += x[j] * x[j];
      }
      wave_reduce2(sv, s2);
      float mean = sv * (1.f / 256.f);
      float var = s2 * (1.f / 256.f) - mean * mean;
      float rs = rsqrtf(var + LN_EPS);
#pragma unroll
      for (int j = 0; j < 4; ++j) {
        int h = lane + 64 * j;
        float y = fmaxf((x[j] - mean) * rs * g2[h] + b2[h], 0.f);
        f2n[((long)n * R_DIM + r2) * H_DIM + h] = f2bf(y);
      }
    }
  }
}

// Sum split-K partials + bias, LN over H, ReLU -> fp32 out. One wave per row.
__global__ __launch_bounds__(64) void ln3_k(
    const float* __restrict__ partial,  // (8, N, H) fp32
    const float* __restrict__ b_out,
    const float* __restrict__ g3, const float* __restrict__ b3,
    float* __restrict__ out)            // (N, H) fp32
{
  const int n = blockIdx.x;
  const int lane = threadIdx.x;
  float x[4], sv = 0.f, s2 = 0.f;
#pragma unroll
  for (int j = 0; j < 4; ++j) {
    int h = lane + 64 * j;
    float v = b_out[h];
#pragma unroll
    for (int ss = 0; ss < 8; ++ss)
      v += partial[((long)ss * N_INST + n) * H_DIM + h];
    x[j] = v; sv += v; s2 += v * v;
  }
  wave_reduce2(sv, s2);
  float mean = sv * (1.f / 256.f);
  float var = s2 * (1.f / 256.f) - mean * mean;
  float rs = rsqrtf(var + LN_EPS);
#pragma unroll
  for (int j = 0; j < 4; ++j) {
    int h = lane + 64 * j;
    float y = fmaxf((x[j] - mean) * rs * g3[h] + b3[h], 0.f);
    out[(long)n * H_DIM + h] = y;
  }
}

extern "C" void kernel_launch(void* const* d_in, const int* in_sizes, int n_in,
                              void* d_out, int out_size, void* d_ws, size_t ws_size,
                              hipStream_t stream) {
  const float* pro  = (const float*)d_in[0];   // (1, N, H) fp32
  const float* roi  = (const float*)d_in[1];   // (R, N, H) fp32
  const float* Wdyn = (const float*)d_in[2];   // (H, 2*H*D) fp32
  const float* bdyn = (const float*)d_in[3];   // (2*H*D,) fp32
  const float* Wout = (const float*)d_in[4];   // (H*R, H) fp32
  const float* bout = (const float*)d_in[5];   // (H,) fp32
  const float* g1 = (const float*)d_in[6];
  const float* b1 = (const float*)d_in[7];
  const float* g2 = (const float*)d_in[8];
  const float* b2 = (const float*)d_in[9];
  const float* g3 = (const float*)d_in[10];
  const float* b3 = (const float*)d_in[11];
  float* out = (float*)d_out;

  // ws layout (bytes):
  //   proB   @ 0          : 1,024,000   (2000*256 bf16)
  //   WdynB  @ 1,024,000  : 16,777,216  (256*32768 bf16)
  //   WoutB  @ 17,801,216 : 6,422,528   (12544*256 bf16)
  //   params @ 24,223,744 : 65,536,000  (2000*16384 bf16; p1 then p2;
  //                                      fp32 split-K partials alias here later)
  //   f1n    @ 89,759,744 : 12,544,000  (2000*49*64 bf16)
  //   f2n    @ 102,303,744: 50,176,000  (2000*49*256 bf16)
  // total ~152.5 MB
  char* ws = (char*)d_ws;
  u16* proB   = (u16*)ws;
  u16* WdynB  = (u16*)(ws + 1024000);
  u16* WoutB  = (u16*)(ws + 17801216);
  u16* params = (u16*)(ws + 24223744);
  u16* f1n    = (u16*)(ws + 89759744);
  u16* f2n    = (u16*)(ws + 102303744);
  float* partial = (float*)(ws + 24223744);

  dim3 blk(256);
  const int HD = H_DIM * D_DIM;  // 16384

  // casts fp32 -> bf16
  castk<<<dim3(500), blk, 0, stream>>>(pro, proB, 512000 / 4);
  castk<<<dim3(8192), blk, 0, stream>>>(Wdyn, WdynB, 8388608 / 4);
  castk<<<dim3(3136), blk, 0, stream>>>(Wout, WoutB, 3211264 / 4);

  // params half 1: p1[n][h][d]
  gemm_bt<<<dim3(32 * 256, 1), blk, 0, stream>>>(
      proB, H_DIM, N_INST, WdynB, 2 * HD, bdyn,
      (void*)params, HD, 0L, 8, 256, 0);
  bmm1_ln<<<dim3(N_INST), blk, 0, stream>>>(roi, params, g1, b1, f1n);
  // params half 2: p2[n][d][h]
  gemm_bt<<<dim3(32 * 256, 1), blk, 0, stream>>>(
      proB, H_DIM, N_INST, WdynB + HD, 2 * HD, bdyn + HD,
      (void*)params, HD, 0L, 8, 256, 0);
  bmm2_ln<<<dim3(N_INST), blk, 0, stream>>>(f1n, params, g2, b2, f2n);
  // out GEMM: (2000 x 12544) @ (12544 x 256), split-K = 8
  gemm_bt<<<dim3(32 * 4, 8), blk, 0, stream>>>(
      f2n, R_DIM * H_DIM, N_INST, WoutB, H_DIM, nullptr,
      (void*)partial, H_DIM, (long)N_INST * H_DIM, 49, 4, 1);
  ln3_k<<<dim3(N_INST), dim3(64), 0, stream>>>(partial, bout, g3, b3, out);
}